// Round 1
// baseline (1222.876 us; speedup 1.0000x reference)
//
#include <hip/hip_runtime.h>
#include <math.h>

#define EPSV 1e-5f

constexpr int N_ = 64, C_ = 64, T_ = 256, V_ = 25;
constexpr int L_ = 3, S_ = 3, IC_ = 16, K_ = 5;
constexpr int TT = 8, TB = T_ / TT;          // 32 t-blocks
constexpr int SITES = TT * V_;               // 200
constexpr int CHTV = T_ * V_;                // 6400 floats per channel plane

// ---------------------------------------------------------------------------
// Kernel 1: down-conv + BN + ReLU, partial sums over the t-tile (for T-mean)
// partial layout: [L][N][TB][IC*V]
// ---------------------------------------------------------------------------
__global__ __launch_bounds__(256, 2)
void k_down_mean(const float* __restrict__ x,
                 const float* __restrict__ w_down,
                 const float* __restrict__ b_down,
                 const float* __restrict__ g_down,
                 const float* __restrict__ bt_down,
                 float* __restrict__ partial) {
    __shared__ float s_wd[L_][IC_][C_];
    __shared__ float s_sd[L_][IC_], s_bd[L_][IC_];
    __shared__ float s_buf[IC_][SITES];
    const int tid = threadIdx.x;
    const int n = blockIdx.x / TB, tb = blockIdx.x % TB;
    const int t0 = tb * TT;

    for (int e = tid; e < L_ * IC_ * C_; e += 256) ((float*)s_wd)[e] = w_down[e];
    if (tid < L_ * IC_) {
        float sd = g_down[tid] / sqrtf(1.f + EPSV);
        ((float*)s_sd)[tid] = sd;
        ((float*)s_bd)[tid] = b_down[tid] * sd + bt_down[tid];
    }
    __syncthreads();

    const bool act = tid < SITES;
    const int tt = tid / V_, v = tid % V_;
    const int t = t0 + tt;
    const size_t base = (size_t)n * C_ * CHTV + (size_t)t * V_ + v;

    for (int i = 0; i < L_; ++i) {
        float dacc[IC_];
#pragma unroll
        for (int c = 0; c < IC_; ++c) dacc[c] = 0.f;
        if (act) {
            for (int ch = 0; ch < 2; ++ch) {
                float xv[32];
#pragma unroll
                for (int q = 0; q < 32; ++q) xv[q] = x[base + (size_t)(ch * 32 + q) * CHTV];
#pragma unroll
                for (int c = 0; c < IC_; ++c) {
                    const float* wr = &s_wd[i][c][ch * 32];
                    float s = dacc[c];
#pragma unroll
                    for (int q = 0; q < 32; ++q) s = fmaf(wr[q], xv[q], s);
                    dacc[c] = s;
                }
            }
        }
        __syncthreads();   // previous iteration's reduce is done
        if (act) {
#pragma unroll
            for (int c = 0; c < IC_; ++c)
                s_buf[c][tid] = fmaxf(fmaf(dacc[c], s_sd[i][c], s_bd[i][c]), 0.f);
        }
        __syncthreads();
        for (int e = tid; e < IC_ * V_; e += 256) {
            int c = e / V_, vv = e % V_;
            float s = 0.f;
#pragma unroll
            for (int q = 0; q < TT; ++q) s += s_buf[c][q * V_ + vv];
            partial[(((size_t)i * N_ + n) * TB + tb) * (IC_ * V_) + e] = s;
        }
    }
}

// ---------------------------------------------------------------------------
// Kernel 2: edge conv per n, summed over layers -> esum[N][IC][V]
// ---------------------------------------------------------------------------
__global__ __launch_bounds__(256, 2)
void k_edge(const float* __restrict__ partial,
            const float* __restrict__ w_edge,
            const float* __restrict__ g_edge,
            const float* __restrict__ bt_edge,
            float* __restrict__ esum) {
    __shared__ float s_xt[V_][IC_];
    __shared__ float s_in[V_][V_];
    __shared__ int   s_id[V_][K_];
    __shared__ float s_we[IC_][2 * IC_];
    __shared__ float s_se[IC_], s_be[IC_];
    const int tid = threadIdx.x;
    const int n = blockIdx.x;
    float eacc[2] = {0.f, 0.f};

    for (int i = 0; i < L_; ++i) {
        __syncthreads();   // protect s_xt / s_we from previous-iter readers
        for (int e = tid; e < IC_ * 2 * IC_; e += 256)
            ((float*)s_we)[e] = w_edge[i * IC_ * 2 * IC_ + e];
        if (tid < IC_) {
            s_se[tid] = g_edge[i * IC_ + tid] / sqrtf(1.f + EPSV);
            s_be[tid] = bt_edge[i * IC_ + tid];
        }
        for (int e = tid; e < IC_ * V_; e += 256) {
            int c = e / V_, v = e % V_;
            float s = 0.f;
            for (int tb = 0; tb < TB; ++tb)
                s += partial[(((size_t)i * N_ + n) * TB + tb) * (IC_ * V_) + e];
            s_xt[v][c] = s * (1.f / T_);
        }
        __syncthreads();
        for (int e = tid; e < V_ * V_; e += 256) {
            int v = e / V_, u = e % V_;
            float s = 0.f;
#pragma unroll
            for (int c = 0; c < IC_; ++c) s += s_xt[v][c] * s_xt[u][c];
            s_in[v][u] = s;
        }
        __syncthreads();
        if (tid < V_) {
            int v = tid;
            float xxv = s_in[v][v];
            unsigned mask = 0;
            for (int k = 0; k < K_; ++k) {
                float best = -1e30f; int bi = 0;
                for (int u = 0; u < V_; ++u) {
                    if (mask & (1u << u)) continue;
                    float pd = 2.f * s_in[v][u] - xxv - s_in[u][u];
                    if (pd > best) { best = pd; bi = u; }   // tie -> lowest u (top_k stable)
                }
                mask |= 1u << bi;
                s_id[v][k] = bi;
            }
        }
        __syncthreads();
#pragma unroll 2
        for (int rep = 0; rep < 2; ++rep) {
            int e = tid + rep * 256;
            if (e < IC_ * V_) {
                int o = e / V_, v = e % V_;
                float bse = 0.f;
#pragma unroll
                for (int c = 0; c < IC_; ++c)
                    bse += s_xt[v][c] * (s_we[o][IC_ + c] - s_we[o][c]);
                float m = -1e30f;
#pragma unroll
                for (int k = 0; k < K_; ++k) {
                    int u = s_id[v][k];
                    float s = bse;
#pragma unroll
                    for (int c = 0; c < IC_; ++c) s += s_xt[u][c] * s_we[o][c];
                    float hb = fmaf(s, s_se[o], s_be[o]);
                    hb = hb >= 0.f ? hb : 0.2f * hb;
                    m = fmaxf(m, hb);
                }
                eacc[rep] += m;
            }
        }
    }
#pragma unroll 2
    for (int rep = 0; rep < 2; ++rep) {
        int e = tid + rep * 256;
        if (e < IC_ * V_) esum[(size_t)n * IC_ * V_ + e] = eacc[rep];
    }
}

// ---------------------------------------------------------------------------
// Kernel 3: fully fused main pass
// ---------------------------------------------------------------------------
__global__ __launch_bounds__(256, 2)
void k_main(const float* __restrict__ x,
            const float* __restrict__ A,
            const float* __restrict__ w_down,
            const float* __restrict__ b_down,
            const float* __restrict__ g_down,
            const float* __restrict__ bt_down,
            const float* __restrict__ w_sub,
            const float* __restrict__ b_sub,
            const float* __restrict__ g_sub,
            const float* __restrict__ bt_sub,
            const float* __restrict__ g_bn,
            const float* __restrict__ b_bn,
            const float* __restrict__ esum,
            float* __restrict__ out) {
    __shared__ float s_A[L_ * S_][V_][28];     // padded to 28 for b128 rows
    __shared__ float s_ws[L_ * S_][IC_][IC_];
    __shared__ float s_wd[L_][IC_][C_];
    __shared__ float s_xd[IC_][TT][28];
    __shared__ float s_sd[L_][IC_], s_bd[L_][IC_];
    __shared__ float s_ss[L_ * S_][IC_], s_sk[L_ * S_][IC_];
    __shared__ float s_sb[C_], s_bb[C_];
    __shared__ float s_es[IC_][V_];
    const int tid = threadIdx.x;
    const int n = blockIdx.x / TB, tb = blockIdx.x % TB;
    const int t0 = tb * TT;

    for (int e = tid; e < L_ * S_ * V_ * 28; e += 256) {
        int ij = e / (V_ * 28), r = e % (V_ * 28), v = r / 28, u = r % 28;
        ((float*)s_A)[e] = (u < V_) ? A[((size_t)ij * V_ + v) * V_ + u] : 0.f;
    }
    for (int e = tid; e < L_ * S_ * IC_ * IC_; e += 256) ((float*)s_ws)[e] = w_sub[e];
    for (int e = tid; e < L_ * IC_ * C_; e += 256) ((float*)s_wd)[e] = w_down[e];
    if (tid < L_ * IC_) {
        float sd = g_down[tid] / sqrtf(1.f + EPSV);
        ((float*)s_sd)[tid] = sd;
        ((float*)s_bd)[tid] = b_down[tid] * sd + bt_down[tid];
    }
    if (tid < L_ * S_ * IC_) {
        float ss = g_sub[tid] / sqrtf(1.f + EPSV);
        ((float*)s_ss)[tid] = ss;
        ((float*)s_sk)[tid] = b_sub[tid] * ss + bt_sub[tid];
    }
    if (tid < C_) {
        s_sb[tid] = g_bn[tid] / sqrtf(1.f + EPSV);
        s_bb[tid] = b_bn[tid];
    }
    for (int e = tid; e < IC_ * V_; e += 256)
        ((float*)s_es)[e] = esum[(size_t)n * IC_ * V_ + e];
    __syncthreads();

    const bool act = tid < SITES;
    const int tt = tid / V_, v = tid % V_;
    const int t = t0 + tt;
    const size_t base = (size_t)n * C_ * CHTV + (size_t)t * V_ + v;

    float acc[48];
#pragma unroll
    for (int q = 0; q < 48; ++q) acc[q] = 0.f;

    for (int i = 0; i < L_; ++i) {
        // ---- phase 1: down conv ----
        float dacc[IC_];
#pragma unroll
        for (int c = 0; c < IC_; ++c) dacc[c] = 0.f;
        if (act) {
            for (int ch = 0; ch < 2; ++ch) {
                float xv[32];
#pragma unroll
                for (int q = 0; q < 32; ++q) xv[q] = x[base + (size_t)(ch * 32 + q) * CHTV];
#pragma unroll
                for (int c = 0; c < IC_; ++c) {
                    const float* wr = &s_wd[i][c][ch * 32];
                    float s = dacc[c];
#pragma unroll
                    for (int q = 0; q < 32; ++q) s = fmaf(wr[q], xv[q], s);
                    dacc[c] = s;
                }
            }
        }
        __syncthreads();   // prev layer's phase-2 readers are done with s_xd
        if (act) {
#pragma unroll
            for (int c = 0; c < IC_; ++c)
                s_xd[c][tt][v] = fmaxf(fmaf(dacc[c], s_sd[i][c], s_bd[i][c]), 0.f);
        }
        __syncthreads();
        // ---- phase 2: graph conv + channel mix, folded BN ----
        if (act) {
#pragma unroll
            for (int j = 0; j < S_; ++j) {
                const int ij = i * S_ + j;
                float ar[V_];
#pragma unroll
                for (int u = 0; u < V_; ++u) ar[u] = s_A[ij][v][u];
                float p[IC_];
#pragma unroll
                for (int c = 0; c < IC_; ++c) {
                    const float* xr = &s_xd[c][tt][0];
                    float s = 0.f;
#pragma unroll
                    for (int u = 0; u < V_; ++u) s = fmaf(xr[u], ar[u], s);
                    p[c] = s;
                }
#pragma unroll
                for (int o = 0; o < IC_; ++o) {
                    const float* wr = &s_ws[ij][o][0];
                    float h = 0.f;
#pragma unroll
                    for (int c = 0; c < IC_; ++c) h = fmaf(wr[c], p[c], h);
                    acc[j * IC_ + o] += fmaf(h, s_ss[ij][o], s_sk[ij][o]);
                }
            }
        }
    }

    // ---- epilogue: final BN + residual + ReLU ----
    if (act) {
#pragma unroll
        for (int chn = 0; chn < 48; ++chn) {
            float val = fmaf(acc[chn], s_sb[chn], s_bb[chn]) + x[base + (size_t)chn * CHTV];
            out[base + (size_t)chn * CHTV] = fmaxf(val, 0.f);
        }
#pragma unroll
        for (int o = 0; o < IC_; ++o) {
            int chn = 48 + o;
            float val = fmaf(s_es[o][v], s_sb[chn], s_bb[chn]) + x[base + (size_t)chn * CHTV];
            out[base + (size_t)chn * CHTV] = fmaxf(val, 0.f);
        }
    }
}

// ---------------------------------------------------------------------------
extern "C" void kernel_launch(void* const* d_in, const int* in_sizes, int n_in,
                              void* d_out, int out_size, void* d_ws, size_t ws_size,
                              hipStream_t stream) {
    (void)in_sizes; (void)n_in; (void)out_size; (void)ws_size;
    const float* x       = (const float*)d_in[0];
    const float* A       = (const float*)d_in[1];
    const float* w_down  = (const float*)d_in[2];
    const float* b_down  = (const float*)d_in[3];
    const float* g_down  = (const float*)d_in[4];
    const float* bt_down = (const float*)d_in[5];
    const float* w_sub   = (const float*)d_in[6];
    const float* b_sub   = (const float*)d_in[7];
    const float* g_sub   = (const float*)d_in[8];
    const float* bt_sub  = (const float*)d_in[9];
    const float* w_edge  = (const float*)d_in[10];
    const float* g_edge  = (const float*)d_in[11];
    const float* bt_edge = (const float*)d_in[12];
    const float* g_bn    = (const float*)d_in[13];
    const float* b_bn    = (const float*)d_in[14];
    float* out = (float*)d_out;

    float* partial = (float*)d_ws;                                  // [3][64][32][400]
    float* esum    = partial + (size_t)L_ * N_ * TB * IC_ * V_;     // [64][400]

    hipLaunchKernelGGL(k_down_mean, dim3(N_ * TB), dim3(256), 0, stream,
                       x, w_down, b_down, g_down, bt_down, partial);
    hipLaunchKernelGGL(k_edge, dim3(N_), dim3(256), 0, stream,
                       partial, w_edge, g_edge, bt_edge, esum);
    hipLaunchKernelGGL(k_main, dim3(N_ * TB), dim3(256), 0, stream,
                       x, A, w_down, b_down, g_down, bt_down,
                       w_sub, b_sub, g_sub, bt_sub, g_bn, b_bn, esum, out);
}

// Round 2
// 248.290 us; speedup vs baseline: 4.9252x; 4.9252x over previous
//
#include <hip/hip_runtime.h>
#include <math.h>

#define EPSV 1e-5f

constexpr int N_ = 64, C_ = 64, T_ = 256, V_ = 25;
constexpr int L_ = 3, S_ = 3, IC_ = 16, K_ = 5;
constexpr int TT = 8, TB = T_ / TT;          // 32 t-blocks
constexpr int SITES = TT * V_;               // 200
constexpr int CHTV = T_ * V_;                // 6400 floats per channel plane
constexpr int XP = 20;                       // c-pad for s_xd rows (bank-conflict-free)
constexpr int AP = 33;                       // row stride for s_A (33v+u mod 32 = v+u -> conflict-free)

// 1/sqrt(1+1e-5)
#define RS 0.99999500003750f

// ---------------------------------------------------------------------------
// k_main: fused down-conv + graph-convs + sub-mix + final BN/residual/ReLU
// for output channels 0..47, AND emits the per-tile partial sums of
// relu(bn(down(x))) needed by the edge branch.
// Weights/BN params are read with wave-uniform indices -> scalar (SMEM) loads.
// LDS holds only A (lane-varying) and the xd exchange tile.
// ---------------------------------------------------------------------------
__global__ __launch_bounds__(256, 4)
void k_main(const float* __restrict__ x,
            const float* __restrict__ A,
            const float* __restrict__ w_down,
            const float* __restrict__ b_down,
            const float* __restrict__ g_down,
            const float* __restrict__ bt_down,
            const float* __restrict__ w_sub,
            const float* __restrict__ b_sub,
            const float* __restrict__ g_sub,
            const float* __restrict__ bt_sub,
            const float* __restrict__ g_bn,
            const float* __restrict__ b_bn,
            float* __restrict__ out,
            float* __restrict__ partial) {
    __shared__ float s_A1[S_][V_ * AP];      // 9.9 KB
    __shared__ float s_xd[TT][V_][XP];       // 16.0 KB, [tt][u][c]

    const int tid = threadIdx.x;
    const int n = blockIdx.x / TB, tb = blockIdx.x % TB;
    const int t0 = tb * TT;
    const bool act = tid < SITES;
    const int tt = tid / V_, v = tid % V_;
    const size_t base = (size_t)n * C_ * CHTV + (size_t)(t0 + tt) * V_ + v;

    float acc[S_][IC_];
#pragma unroll
    for (int j = 0; j < S_; ++j)
#pragma unroll
        for (int o = 0; o < IC_; ++o) acc[j][o] = 0.f;

    for (int i = 0; i < L_; ++i) {
        __syncthreads();   // B1: prev layer's s_A / s_xd readers done
        // ---- stage A for layer i (lane-varying reads later -> LDS) ----
        for (int e = tid; e < S_ * V_ * V_; e += 256) {
            int j = e / (V_ * V_), r = e % (V_ * V_), vv = r / V_, u = r % V_;
            s_A1[j][vv * AP + u] = A[((size_t)(i * S_ + j) * V_ + vv) * V_ + u];
        }
        // ---- phase 1: down conv (weights via uniform scalar loads) ----
        if (act) {
            float dacc[IC_];
#pragma unroll
            for (int c = 0; c < IC_; ++c) dacc[c] = 0.f;
            for (int ch2 = 0; ch2 < 2; ++ch2) {
                float xv[32];
#pragma unroll
                for (int q = 0; q < 32; ++q)
                    xv[q] = x[base + (size_t)(ch2 * 32 + q) * CHTV];
#pragma unroll
                for (int c = 0; c < IC_; ++c) {
                    const float* wr = &w_down[(i * IC_ + c) * C_ + ch2 * 32];
                    float s = dacc[c];
#pragma unroll
                    for (int q = 0; q < 32; ++q) s = fmaf(wr[q], xv[q], s);
                    dacc[c] = s;
                }
            }
#pragma unroll
            for (int c = 0; c < IC_; ++c) {
                float sd = g_down[i * IC_ + c] * RS;
                float bd = fmaf(b_down[i * IC_ + c], sd, bt_down[i * IC_ + c]);
                s_xd[tt][v][c] = fmaxf(fmaf(dacc[c], sd, bd), 0.f);
            }
        }
        __syncthreads();   // B2: s_xd + s_A1 ready
        // ---- phase 2: graph conv (xd read once, reused across all 3 j) ----
        if (act) {
            float p[S_][IC_];
#pragma unroll
            for (int j = 0; j < S_; ++j)
#pragma unroll
                for (int c = 0; c < IC_; ++c) p[j][c] = 0.f;
            for (int u = 0; u < V_; ++u) {
                const float* xr = &s_xd[tt][u][0];
                float4 xa = *(const float4*)(xr + 0);
                float4 xb = *(const float4*)(xr + 4);
                float4 xc = *(const float4*)(xr + 8);
                float4 xe = *(const float4*)(xr + 12);
                float xv4[16] = {xa.x, xa.y, xa.z, xa.w, xb.x, xb.y, xb.z, xb.w,
                                 xc.x, xc.y, xc.z, xc.w, xe.x, xe.y, xe.z, xe.w};
                float a[S_];
#pragma unroll
                for (int j = 0; j < S_; ++j) a[j] = s_A1[j][v * AP + u];
#pragma unroll
                for (int j = 0; j < S_; ++j)
#pragma unroll
                    for (int c = 0; c < IC_; ++c)
                        p[j][c] = fmaf(a[j], xv4[c], p[j][c]);
            }
            // ---- channel mix + folded sub-BN (uniform scalar weight loads) ----
#pragma unroll
            for (int j = 0; j < S_; ++j) {
#pragma unroll
                for (int o = 0; o < IC_; ++o) {
                    const int gi = (i * S_ + j) * IC_ + o;
                    const float* wr = &w_sub[(size_t)gi * IC_];
                    float h = 0.f;
#pragma unroll
                    for (int c = 0; c < IC_; ++c) h = fmaf(wr[c], p[j][c], h);
                    float ss = g_sub[gi] * RS;
                    float sk = fmaf(b_sub[gi], ss, bt_sub[gi]);
                    acc[j][o] += fmaf(h, ss, sk);
                }
            }
        }
        // ---- edge-branch partial sums over this t-tile (reads s_xd) ----
        for (int e = tid; e < IC_ * V_; e += 256) {
            int c = e / V_, vv = e % V_;
            float s = 0.f;
#pragma unroll
            for (int q = 0; q < TT; ++q) s += s_xd[q][vv][c];
            partial[(((size_t)i * N_ + n) * TB + tb) * (IC_ * V_) + e] = s;
        }
    }

    // ---- epilogue: final BN + residual + ReLU for channels 0..47 ----
    if (act) {
#pragma unroll
        for (int j = 0; j < S_; ++j)
#pragma unroll
            for (int o = 0; o < IC_; ++o) {
                const int chn = j * IC_ + o;
                float sb = g_bn[chn] * RS;
                float val = fmaf(acc[j][o], sb, b_bn[chn]) + x[base + (size_t)chn * CHTV];
                out[base + (size_t)chn * CHTV] = fmaxf(val, 0.f);
            }
    }
}

// ---------------------------------------------------------------------------
// k_edge: per-n top-k + edge conv, summed over layers -> esum[N][IC][V]
// ---------------------------------------------------------------------------
__global__ __launch_bounds__(256, 2)
void k_edge(const float* __restrict__ partial,
            const float* __restrict__ w_edge,
            const float* __restrict__ g_edge,
            const float* __restrict__ bt_edge,
            float* __restrict__ esum) {
    __shared__ float s_xt[V_][IC_];
    __shared__ float s_in[V_][V_];
    __shared__ int   s_id[V_][K_];
    __shared__ float s_we[IC_][2 * IC_];
    __shared__ float s_se[IC_], s_be[IC_];
    const int tid = threadIdx.x;
    const int n = blockIdx.x;
    float eacc[2] = {0.f, 0.f};

    for (int i = 0; i < L_; ++i) {
        __syncthreads();
        for (int e = tid; e < IC_ * 2 * IC_; e += 256)
            ((float*)s_we)[e] = w_edge[i * IC_ * 2 * IC_ + e];
        if (tid < IC_) {
            s_se[tid] = g_edge[i * IC_ + tid] * RS;
            s_be[tid] = bt_edge[i * IC_ + tid];
        }
        for (int e = tid; e < IC_ * V_; e += 256) {
            int c = e / V_, v = e % V_;
            float s = 0.f;
            for (int tb = 0; tb < TB; ++tb)
                s += partial[(((size_t)i * N_ + n) * TB + tb) * (IC_ * V_) + e];
            s_xt[v][c] = s * (1.f / T_);
        }
        __syncthreads();
        for (int e = tid; e < V_ * V_; e += 256) {
            int v = e / V_, u = e % V_;
            float s = 0.f;
#pragma unroll
            for (int c = 0; c < IC_; ++c) s += s_xt[v][c] * s_xt[u][c];
            s_in[v][u] = s;
        }
        __syncthreads();
        if (tid < V_) {
            int v = tid;
            float xxv = s_in[v][v];
            unsigned mask = 0;
            for (int k = 0; k < K_; ++k) {
                float best = -1e30f; int bi = 0;
                for (int u = 0; u < V_; ++u) {
                    if (mask & (1u << u)) continue;
                    float pd = 2.f * s_in[v][u] - xxv - s_in[u][u];
                    if (pd > best) { best = pd; bi = u; }   // tie -> lowest u
                }
                mask |= 1u << bi;
                s_id[v][k] = bi;
            }
        }
        __syncthreads();
#pragma unroll 2
        for (int rep = 0; rep < 2; ++rep) {
            int e = tid + rep * 256;
            if (e < IC_ * V_) {
                int o = e / V_, v = e % V_;
                float bse = 0.f;
#pragma unroll
                for (int c = 0; c < IC_; ++c)
                    bse += s_xt[v][c] * (s_we[o][IC_ + c] - s_we[o][c]);
                float m = -1e30f;
#pragma unroll
                for (int k = 0; k < K_; ++k) {
                    int u = s_id[v][k];
                    float s = bse;
#pragma unroll
                    for (int c = 0; c < IC_; ++c) s += s_xt[u][c] * s_we[o][c];
                    float hb = fmaf(s, s_se[o], s_be[o]);
                    hb = hb >= 0.f ? hb : 0.2f * hb;
                    m = fmaxf(m, hb);
                }
                eacc[rep] += m;
            }
        }
    }
#pragma unroll 2
    for (int rep = 0; rep < 2; ++rep) {
        int e = tid + rep * 256;
        if (e < IC_ * V_) esum[(size_t)n * IC_ * V_ + e] = eacc[rep];
    }
}

// ---------------------------------------------------------------------------
// k_edge_out: out channels 48..63 = relu(bn(esum) + x), broadcast over T
// vectorized float4 over the (T*V) plane
// ---------------------------------------------------------------------------
__global__ __launch_bounds__(256)
void k_edge_out(const float* __restrict__ x,
                const float* __restrict__ esum,
                const float* __restrict__ g_bn,
                const float* __restrict__ b_bn,
                float* __restrict__ out) {
    const int gid = blockIdx.x * 256 + threadIdx.x;     // [0, 64*16*1600)
    const int n = gid / (IC_ * 1600);
    const int r = gid % (IC_ * 1600);
    const int o = r / 1600;
    const int q = r % 1600;
    const int chn = 48 + o;
    const size_t fo = ((size_t)n * C_ + chn) * 1600 + q;   // float4 index
    float4 xv = ((const float4*)x)[fo];
    float sb = g_bn[chn] * RS;
    float bb = b_bn[chn];
    const float* es = &esum[(size_t)n * IC_ * V_ + o * V_];
    float4 ov;
    {
        int p = q * 4;
        float r0 = fmaf(es[(p + 0) % V_], sb, bb) + xv.x;
        float r1 = fmaf(es[(p + 1) % V_], sb, bb) + xv.y;
        float r2 = fmaf(es[(p + 2) % V_], sb, bb) + xv.z;
        float r3 = fmaf(es[(p + 3) % V_], sb, bb) + xv.w;
        ov.x = fmaxf(r0, 0.f); ov.y = fmaxf(r1, 0.f);
        ov.z = fmaxf(r2, 0.f); ov.w = fmaxf(r3, 0.f);
    }
    ((float4*)out)[fo] = ov;
}

// ---------------------------------------------------------------------------
extern "C" void kernel_launch(void* const* d_in, const int* in_sizes, int n_in,
                              void* d_out, int out_size, void* d_ws, size_t ws_size,
                              hipStream_t stream) {
    (void)in_sizes; (void)n_in; (void)out_size; (void)ws_size;
    const float* x       = (const float*)d_in[0];
    const float* A       = (const float*)d_in[1];
    const float* w_down  = (const float*)d_in[2];
    const float* b_down  = (const float*)d_in[3];
    const float* g_down  = (const float*)d_in[4];
    const float* bt_down = (const float*)d_in[5];
    const float* w_sub   = (const float*)d_in[6];
    const float* b_sub   = (const float*)d_in[7];
    const float* g_sub   = (const float*)d_in[8];
    const float* bt_sub  = (const float*)d_in[9];
    const float* w_edge  = (const float*)d_in[10];
    const float* g_edge  = (const float*)d_in[11];
    const float* bt_edge = (const float*)d_in[12];
    const float* g_bn    = (const float*)d_in[13];
    const float* b_bn    = (const float*)d_in[14];
    float* out = (float*)d_out;

    float* partial = (float*)d_ws;                                  // [3][64][32][400]
    float* esum    = partial + (size_t)L_ * N_ * TB * IC_ * V_;     // [64][400]

    hipLaunchKernelGGL(k_main, dim3(N_ * TB), dim3(256), 0, stream,
                       x, A, w_down, b_down, g_down, bt_down,
                       w_sub, b_sub, g_sub, bt_sub, g_bn, b_bn, out, partial);
    hipLaunchKernelGGL(k_edge, dim3(N_), dim3(256), 0, stream,
                       partial, w_edge, g_edge, bt_edge, esum);
    hipLaunchKernelGGL(k_edge_out, dim3(N_ * IC_ * 1600 / 256), dim3(256), 0, stream,
                       x, esum, g_bn, b_bn, out);
}